// Round 1
// baseline (934.744 us; speedup 1.0000x reference)
//
#include <hip/hip_runtime.h>
#include <cmath>

#define B_ 64
#define L_ 200
#define H_ 128
#define S_ 64
#define E_ 256
#define K_ 101
#define NROW (B_ * L_)

__device__ __forceinline__ float wave_sum64(float v) {
#pragma unroll
  for (int o = 32; o > 0; o >>= 1) v += __shfl_xor(v, o, 64);
  return v;
}

__device__ __forceinline__ float block_sum_256(float v, volatile float* red) {
  v = wave_sum64(v);
  int w = threadIdx.x >> 6;
  __syncthreads();  // protect red reuse across calls
  if ((threadIdx.x & 63) == 0) red[w] = v;
  __syncthreads();
  return red[0] + red[1] + red[2] + red[3];
}

// x[b,l,h] = (item_emb[seq] + pos_emb[l]) * mask
__global__ void embed_kernel(const int* __restrict__ seqs, const float* __restrict__ emb,
                             const float* __restrict__ pos, float* __restrict__ x) {
  int r = blockIdx.x;          // b*L + l
  int h = threadIdx.x;         // 128
  int l = r % L_;
  int idx = seqs[r];
  float val = (idx != 0) ? (emb[(size_t)idx * H_ + h] + pos[l * H_ + h]) : 0.f;
  x[(size_t)r * H_ + h] = val;
}

// LayerNorm over H=128, one wave per row (2 elems/thread)
__global__ void ln_h_kernel(const float* __restrict__ x, const float* __restrict__ g,
                            const float* __restrict__ b, float* __restrict__ u) {
  int r = blockIdx.x;
  int t = threadIdx.x;  // 64
  float v0 = x[(size_t)r * H_ + t];
  float v1 = x[(size_t)r * H_ + 64 + t];
  float mean = wave_sum64(v0 + v1) * (1.f / 128.f);
  float d0 = v0 - mean, d1 = v1 - mean;
  float var = wave_sum64(d0 * d0 + d1 * d1) * (1.f / 128.f);
  float rs = rsqrtf(var + 1e-5f);
  u[(size_t)r * H_ + t]      = d0 * rs * g[t] + b[t];
  u[(size_t)r * H_ + 64 + t] = d1 * rs * g[64 + t] + b[64 + t];
}

// Final LN only at l = L-1, write xf[b,H]
__global__ void ln_final_kernel(const float* __restrict__ x, const float* __restrict__ g,
                                const float* __restrict__ b, float* __restrict__ xf) {
  int bb = blockIdx.x;
  int t = threadIdx.x;  // 64
  size_t r = (size_t)bb * L_ + (L_ - 1);
  float v0 = x[r * H_ + t];
  float v1 = x[r * H_ + 64 + t];
  float mean = wave_sum64(v0 + v1) * (1.f / 128.f);
  float d0 = v0 - mean, d1 = v1 - mean;
  float var = wave_sum64(d0 * d0 + d1 * d1) * (1.f / 128.f);
  float rs = rsqrtf(var + 1e-5f);
  xf[bb * H_ + t]      = d0 * rs * g[t] + b[t];
  xf[bb * H_ + 64 + t] = d1 * rs * g[64 + t] + b[64 + t];
}

// Tiled fp32 GEMM: C[M,N] = A[M,K] @ W[K,N] + bias
// EPI==1: C = (C_old + val) * mask[row]  (residual+mask epilogue)
template <int EPI>
__global__ __launch_bounds__(256) void gemm_kernel(
    const float* __restrict__ A, const float* __restrict__ W,
    const float* __restrict__ bias, float* __restrict__ C,
    int M, int N, int K, const int* __restrict__ seqs) {
  __shared__ float As[64][20];  // [m][k], pad to 20 for aligned float4 stores
  __shared__ float Bs[16][64];  // [k][n]
  const int tid = threadIdx.x;
  const int tx = tid & 15;   // n-dir
  const int ty = tid >> 4;   // m-dir
  const int m0 = blockIdx.y * 64;
  const int n0 = blockIdx.x * 64;

  const int a_m = tid >> 2;
  const int a_k = (tid & 3) << 2;
  const int b_k = tid >> 4;
  const int b_n = (tid & 15) << 2;

  float acc[4][4] = {{0.f, 0.f, 0.f, 0.f}, {0.f, 0.f, 0.f, 0.f},
                     {0.f, 0.f, 0.f, 0.f}, {0.f, 0.f, 0.f, 0.f}};

  for (int k0 = 0; k0 < K; k0 += 16) {
    float4 av = *(const float4*)(A + (size_t)(m0 + a_m) * K + k0 + a_k);
    float4 bv = *(const float4*)(W + (size_t)(b_k + k0) * N + n0 + b_n);
    *(float4*)&As[a_m][a_k] = av;
    *(float4*)&Bs[b_k][b_n] = bv;
    __syncthreads();
#pragma unroll
    for (int kk = 0; kk < 16; ++kk) {
      float4 b4 = *(const float4*)&Bs[kk][tx << 2];
      float a0 = As[ty * 4 + 0][kk];
      float a1 = As[ty * 4 + 1][kk];
      float a2 = As[ty * 4 + 2][kk];
      float a3 = As[ty * 4 + 3][kk];
      acc[0][0] += a0 * b4.x; acc[0][1] += a0 * b4.y; acc[0][2] += a0 * b4.z; acc[0][3] += a0 * b4.w;
      acc[1][0] += a1 * b4.x; acc[1][1] += a1 * b4.y; acc[1][2] += a1 * b4.z; acc[1][3] += a1 * b4.w;
      acc[2][0] += a2 * b4.x; acc[2][1] += a2 * b4.y; acc[2][2] += a2 * b4.z; acc[2][3] += a2 * b4.w;
      acc[3][0] += a3 * b4.x; acc[3][1] += a3 * b4.y; acc[3][2] += a3 * b4.z; acc[3][3] += a3 * b4.w;
    }
    __syncthreads();
  }

  float4 bz = *(const float4*)(bias + n0 + (tx << 2));
#pragma unroll
  for (int i = 0; i < 4; ++i) {
    int row = m0 + ty * 4 + i;
    float* cp = C + (size_t)row * N + n0 + (tx << 2);
    float4 val;
    val.x = acc[i][0] + bz.x;
    val.y = acc[i][1] + bz.y;
    val.z = acc[i][2] + bz.z;
    val.w = acc[i][3] + bz.w;
    if (EPI == 1) {
      float msk = (seqs[row] != 0) ? 1.f : 0.f;
      float4 old = *(const float4*)cp;
      val.x = (old.x + val.x) * msk;
      val.y = (old.y + val.y) * msk;
      val.z = (old.z + val.z) * msk;
      val.w = (old.w + val.w) * msk;
    }
    *(float4*)cp = val;
  }
}

// Depthwise conv (k=3, symmetric pad 1, cross-correlation) + bias + silu.
// Reads x-half of xz ([.,512] rows, cols 0:256); writes xc [.,256] and xsum[row].
__global__ void conv_silu_kernel(const float* __restrict__ xz, const float* __restrict__ cw,
                                 const float* __restrict__ cb, float* __restrict__ xc,
                                 float* __restrict__ xsum) {
  __shared__ float red[4];
  int r = blockIdx.x;   // b*L + l
  int e = threadIdx.x;  // 256
  int l = r % L_;
  float w0 = cw[e * 3 + 0], w1 = cw[e * 3 + 1], w2 = cw[e * 3 + 2];
  float xm1 = (l > 0)      ? xz[(size_t)(r - 1) * 512 + e] : 0.f;
  float x0  =                xz[(size_t)r * 512 + e];
  float xp1 = (l < L_ - 1) ? xz[(size_t)(r + 1) * 512 + e] : 0.f;
  float v = w0 * xm1 + w1 * x0 + w2 * xp1 + cb[e];
  float sv = v / (1.f + expf(-v));  // silu
  xc[(size_t)r * E_ + e] = sv;
  float tot = block_sum_256(sv, red);
  if (threadIdx.x == 0) xsum[r] = tot;
}

// Sequential scan, collapsed state h[S] per batch. Outputs s[b,t] = C_t . h_t.
__global__ __launch_bounds__(256) void scan_kernel(
    const float* __restrict__ ssm,   // [B*L, 192]: delta_raw | Bm | Cm
    const float* __restrict__ xs,    // [B*L]
    const float* __restrict__ A_log, // [S] (block-offset applied by caller)
    float* __restrict__ s_out) {     // [B*L]
  __shared__ float A_s[64], h_s[64], delta_s[64], C_s[64], part[4][64];
  int b = blockIdx.x;
  int tid = threadIdx.x;
  int i = tid & 63;
  int q = tid >> 6;  // 0..3

  if (tid < 64) {
    float al = fminf(fmaxf(A_log[tid], -5.f), 5.f);
    A_s[tid] = -expf(al);
    h_s[tid] = 0.f;
  }
  __syncthreads();

  for (int t = 0; t < L_; ++t) {
    const float* row = ssm + ((size_t)b * L_ + t) * 192;
    float xs_t = xs[b * L_ + t];
    float dB_reg = 0.f;
    if (tid < 64) {
      float dr = row[tid];
      float d = fmaxf(dr, 0.f) + log1pf(expf(-fabsf(dr)));  // softplus
      delta_s[tid] = d;
      dB_reg = d * row[64 + tid];
      C_s[tid] = row[128 + tid];
    }
    __syncthreads();
    float di = delta_s[i];
    float p = 0.f;
#pragma unroll
    for (int jj = 0; jj < 16; ++jj) {
      int j = (q << 4) + jj;
      float e = fminf(fmaxf(di * A_s[j], -10.f), 0.f);
      p += expf(e) * h_s[j];
    }
    part[q][i] = p;
    __syncthreads();
    if (tid < 64) {
      float hn = part[0][i] + part[1][i] + part[2][i] + part[3][i] + dB_reg * xs_t;
      hn = fminf(fmaxf(hn, -100.f), 100.f);
      h_s[i] = hn;
      float val = wave_sum64(hn * C_s[i]);
      if (i == 0) s_out[b * L_ + t] = val;
    }
    __syncthreads();
  }
}

// y = s + D*xc ; yln = LN_E(y) ; v = yln * silu(z)
__global__ void gate_kernel(const float* __restrict__ s, const float* __restrict__ xc,
                            const float* __restrict__ xz, const float* __restrict__ D,
                            const float* __restrict__ g, const float* __restrict__ bb,
                            float* __restrict__ v) {
  __shared__ float red[4];
  int r = blockIdx.x;
  int e = threadIdx.x;  // 256
  float y = s[r] + D[e] * xc[(size_t)r * E_ + e];
  float mean = block_sum_256(y, red) * (1.f / 256.f);
  float d = y - mean;
  float var = block_sum_256(d * d, red) * (1.f / 256.f);
  float yln = d * rsqrtf(var + 1e-5f) * g[e] + bb[e];
  float z = xz[(size_t)r * 512 + 256 + e];
  v[(size_t)r * E_ + e] = yln * (z / (1.f + expf(-z)));
}

// logits[b,k] = xf[b,:] . item_emb[item_idxs[b,k], :]
__global__ void logits_kernel(const float* __restrict__ xf, const int* __restrict__ idxs,
                              const float* __restrict__ emb, float* __restrict__ out) {
  int p = blockIdx.x;  // b*K + k
  int b = p / K_;
  int t = threadIdx.x;  // 64
  int id = idxs[p];
  float a = xf[b * H_ + t] * emb[(size_t)id * H_ + t] +
            xf[b * H_ + 64 + t] * emb[(size_t)id * H_ + 64 + t];
  a = wave_sum64(a);
  if (t == 0) out[p] = a;
}

extern "C" void kernel_launch(void* const* d_in, const int* in_sizes, int n_in,
                              void* d_out, int out_size, void* d_ws, size_t ws_size,
                              hipStream_t stream) {
  const int*   seqs   = (const int*)d_in[0];
  const int*   idxs   = (const int*)d_in[1];
  const float* emb    = (const float*)d_in[2];
  const float* pos    = (const float*)d_in[3];
  const float* blk_g  = (const float*)d_in[4];
  const float* blk_b  = (const float*)d_in[5];
  const float* in_w   = (const float*)d_in[6];
  const float* in_b   = (const float*)d_in[7];
  const float* conv_w = (const float*)d_in[8];
  const float* conv_b = (const float*)d_in[9];
  const float* xp_w   = (const float*)d_in[10];
  const float* xp_b   = (const float*)d_in[11];
  const float* A_log  = (const float*)d_in[12];
  const float* D_p    = (const float*)d_in[13];
  const float* out_w  = (const float*)d_in[14];
  const float* out_b  = (const float*)d_in[15];
  const float* ig     = (const float*)d_in[16];
  const float* ib     = (const float*)d_in[17];
  const float* fg     = (const float*)d_in[18];
  const float* fb     = (const float*)d_in[19];
  float* out = (float*)d_out;
  float* ws = (float*)d_ws;

  // workspace layout (floats); total ~18.9M floats ~= 75.5 MB
  float* x   = ws;               // [12800,128]
  float* u   = ws + 1638400;     // [12800,128]
  float* xz  = ws + 3276800;     // [12800,512]
  float* xc  = ws + 9830400;     // [12800,256]
  float* ssm = ws + 13107200;    // [12800,192]
  float* v   = ws + 15564800;    // [12800,256]
  float* xs  = ws + 18841600;    // [12800]
  float* sA  = ws + 18854400;    // [12800]
  float* xf  = ws + 18867200;    // [64,128]

  embed_kernel<<<NROW, 128, 0, stream>>>(seqs, emb, pos, x);

  for (int blk = 0; blk < 2; ++blk) {
    ln_h_kernel<<<NROW, 64, 0, stream>>>(x, blk_g + blk * H_, blk_b + blk * H_, u);
    gemm_kernel<0><<<dim3(512 / 64, NROW / 64), 256, 0, stream>>>(
        u, in_w + (size_t)blk * H_ * 2 * E_, in_b + blk * 2 * E_, xz, NROW, 512, 128, nullptr);
    conv_silu_kernel<<<NROW, 256, 0, stream>>>(xz, conv_w + blk * E_ * 3, conv_b + blk * E_,
                                               xc, xs);
    gemm_kernel<0><<<dim3(192 / 64, NROW / 64), 256, 0, stream>>>(
        xc, xp_w + (size_t)blk * E_ * 3 * S_, xp_b + blk * 3 * S_, ssm, NROW, 192, 256, nullptr);
    scan_kernel<<<B_, 256, 0, stream>>>(ssm, xs, A_log + blk * S_, sA);
    gate_kernel<<<NROW, 256, 0, stream>>>(sA, xc, xz, D_p + blk * E_, ig + blk * E_,
                                          ib + blk * E_, v);
    gemm_kernel<1><<<dim3(128 / 64, NROW / 64), 256, 0, stream>>>(
        v, out_w + (size_t)blk * E_ * H_, out_b + blk * H_, x, NROW, 128, 256, seqs);
  }

  ln_final_kernel<<<B_, 64, 0, stream>>>(x, fg, fb, xf);
  logits_kernel<<<B_ * K_, 64, 0, stream>>>(xf, idxs, emb, out);
}